// Round 4
// baseline (336.791 us; speedup 1.0000x reference)
//
#include <hip/hip_runtime.h>
#include <math.h>
#include <stdint.h>

#define BS   16
#define CH   256
#define NPIX 16384        // 128*128
#define TOPK 12
#define WPB  (NPIX / 64)  // 256 uint64 mask words per batch

// clang-native vectors so __builtin_nontemporal_load accepts them
typedef float nfloat4 __attribute__((ext_vector_type(4)));

// ---------------------------------------------------------------------------
// Kernel A: softmax over the 2 logit channels -> fg/bg threshold bits, packed
// via __ballot. Interleaved layout: mask[b*WPB*2 + w*2 + {0,1}] = {fg,bg}
// so the consumer can fetch both with one b128 read.
// Grid: BS * (NPIX/256) = 1024 blocks of 256.
// ---------------------------------------------------------------------------
__global__ __launch_bounds__(256) void mask_kernel(
    const float* __restrict__ outp,   // (BS, 2, NPIX)
    const float* __restrict__ tau,    // scalar
    uint64_t* __restrict__ mask)      // (BS, WPB, 2) interleaved fg/bg bits
{
    int b = blockIdx.x >> 6;                       // 64 blocks per batch
    int n = ((blockIdx.x & 63) << 8) + threadIdx.x;

    float t = tau[0];
    float fthres = 1.0f / (1.0f + expf(-t));       // sigmoid(tau)
    float bthres = 1.0f - fthres;

    float o0 = outp[((size_t)b * 2    ) * NPIX + n];
    float o1 = outp[((size_t)b * 2 + 1) * NPIX + n];
    // mirror jax.nn.softmax: exp(x - max) / sum
    float m  = fmaxf(o0, o1);
    float e0 = expf(o0 - m);
    float e1 = expf(o1 - m);
    float inv = 1.0f / (e0 + e1);

    int fg = (e1 * inv) > fthres;   // pred_fg > fg_thres
    int bg = (e0 * inv) > bthres;   // pred_bg > bg_thres

    uint64_t bf = __ballot(fg);
    uint64_t bb = __ballot(bg);
    if ((threadIdx.x & 63) == 0) {
        int w = n >> 6;
        mask[((size_t)b * WPB + w) * 2    ] = bf;
        mask[((size_t)b * WPB + w) * 2 + 1] = bb;
    }
}

// ---------------------------------------------------------------------------
// Kernel B (HBM-bound): per (b,c) masked fg/bg sums over NPIX in one pass.
// Mask bits preloaded to LDS (4 KB, interleaved) -> one ds_read_b128 per
// iteration. Two accumulator pairs shorten the dependent-add chain.
// Writes RAW SUMS: d_out[0..BS*CH) = fg, d_out[BS*CH..2*BS*CH) = bg.
// Grid: BS*CH = 4096 blocks of 256; each block streams 64 KB of feat.
// ---------------------------------------------------------------------------
__global__ __launch_bounds__(256) void sum_kernel(
    const float* __restrict__ feat,           // (BS, CH, NPIX)
    const uint64_t* __restrict__ mask,        // (BS, WPB, 2)
    float* __restrict__ dout)
{
    int b = blockIdx.x >> 8;
    int c = blockIdx.x & (CH - 1);

    __shared__ uint64_t lm[WPB][2];
    ((uint64_t*)lm)[threadIdx.x]       = mask[(size_t)b * WPB * 2 + threadIdx.x];
    ((uint64_t*)lm)[256 + threadIdx.x] = mask[(size_t)b * WPB * 2 + 256 + threadIdx.x];
    __syncthreads();

    const nfloat4* fp = (const nfloat4*)(feat + (((size_t)b * CH + c) << 14));

    float sf0 = 0.0f, sb0 = 0.0f, sf1 = 0.0f, sb1 = 0.0f;
    #pragma unroll
    for (int i = 0; i < 16; i += 2) {
        {
            int idx = i * 256 + threadIdx.x;
            nfloat4 f = __builtin_nontemporal_load(&fp[idx]);
            int p = idx << 2;
            unsigned fb = (unsigned)(lm[p >> 6][0] >> (p & 63)) & 0xF;
            unsigned bb = (unsigned)(lm[p >> 6][1] >> (p & 63)) & 0xF;
            if (fb & 1) sf0 += f.x;
            if (fb & 2) sf0 += f.y;
            if (fb & 4) sf0 += f.z;
            if (fb & 8) sf0 += f.w;
            if (bb & 1) sb0 += f.x;
            if (bb & 2) sb0 += f.y;
            if (bb & 4) sb0 += f.z;
            if (bb & 8) sb0 += f.w;
        }
        {
            int idx = (i + 1) * 256 + threadIdx.x;
            nfloat4 f = __builtin_nontemporal_load(&fp[idx]);
            int p = idx << 2;
            unsigned fb = (unsigned)(lm[p >> 6][0] >> (p & 63)) & 0xF;
            unsigned bb = (unsigned)(lm[p >> 6][1] >> (p & 63)) & 0xF;
            if (fb & 1) sf1 += f.x;
            if (fb & 2) sf1 += f.y;
            if (fb & 4) sf1 += f.z;
            if (fb & 8) sf1 += f.w;
            if (bb & 1) sb1 += f.x;
            if (bb & 2) sb1 += f.y;
            if (bb & 4) sb1 += f.z;
            if (bb & 8) sb1 += f.w;
        }
    }
    float sfg = sf0 + sf1;
    float sbg = sb0 + sb1;

    // 64-lane wave reduction, then cross-wave via LDS
    #pragma unroll
    for (int off = 32; off > 0; off >>= 1) {
        sfg += __shfl_down(sfg, off);
        sbg += __shfl_down(sbg, off);
    }
    __shared__ float shf[4], shb[4];
    int lane = threadIdx.x & 63, wid = threadIdx.x >> 6;
    if (lane == 0) { shf[wid] = sfg; shb[wid] = sbg; }
    __syncthreads();
    if (threadIdx.x == 0) {
        dout[b * CH + c]           = shf[0] + shf[1] + shf[2] + shf[3];
        dout[BS * CH + b * CH + c] = shb[0] + shb[1] + shb[2] + shb[3];
    }
}

// ---------------------------------------------------------------------------
// Kernel C: finalize. One block per (b, which): 2*BS = 32 blocks, 256 thr.
// cnt from popcount of the packed mask. cnt>0: divide in place. cnt==0
// (rare, block-uniform): exact top-12 (desc value, asc index — matches
// jax.lax.top_k) of the softmax prob, then per-channel gather-mean.
// ---------------------------------------------------------------------------
__global__ __launch_bounds__(256) void finalize_kernel(
    const float* __restrict__ feat,
    const float* __restrict__ outp,
    const uint64_t* __restrict__ mask,
    float* __restrict__ dout)
{
    int b     = blockIdx.x >> 1;
    int which = blockIdx.x & 1;   // 0 = fg, 1 = bg
    float* o = dout + (size_t)which * BS * CH + (size_t)b * CH;

    // popcount-reduce the batch's 256 interleaved mask words
    int pc = (int)__popcll(mask[((size_t)b * WPB + threadIdx.x) * 2 + which]);
    #pragma unroll
    for (int off = 32; off > 0; off >>= 1) pc += __shfl_down(pc, off);
    __shared__ int sw[4];
    if ((threadIdx.x & 63) == 0) sw[threadIdx.x >> 6] = pc;
    __syncthreads();
    int cnt = sw[0] + sw[1] + sw[2] + sw[3];

    if (cnt > 0) {
        o[threadIdx.x] = o[threadIdx.x] / (float)cnt;
        return;
    }

    // ---- top-k fallback (block-uniform branch) ----
    __shared__ int   sel[TOPK];
    __shared__ float shv[256];
    __shared__ int   shi[256];

    const float* o0p = outp + ((size_t)b * 2) * NPIX;
    const float* o1p = o0p + NPIX;

    for (int k = 0; k < TOPK; ++k) {
        float bestv = -INFINITY;
        int   besti = 0x7fffffff;
        for (int n = threadIdx.x; n < NPIX; n += 256) {
            bool skip = false;
            for (int j = 0; j < k; ++j) if (sel[j] == n) { skip = true; break; }
            if (skip) continue;
            float a0 = o0p[n], a1 = o1p[n];
            float m  = fmaxf(a0, a1);
            float e0 = expf(a0 - m);
            float e1 = expf(a1 - m);
            float p  = (which == 0 ? e1 : e0) / (e0 + e1);
            if (p > bestv || (p == bestv && n < besti)) { bestv = p; besti = n; }
        }
        shv[threadIdx.x] = bestv;
        shi[threadIdx.x] = besti;
        __syncthreads();
        for (int off = 128; off > 0; off >>= 1) {
            if (threadIdx.x < off) {
                float v2 = shv[threadIdx.x + off];
                int   i2 = shi[threadIdx.x + off];
                if (v2 > shv[threadIdx.x] ||
                    (v2 == shv[threadIdx.x] && i2 < shi[threadIdx.x])) {
                    shv[threadIdx.x] = v2;
                    shi[threadIdx.x] = i2;
                }
            }
            __syncthreads();
        }
        if (threadIdx.x == 0) sel[k] = shi[0];
        __syncthreads();
    }

    const float* fb = feat + ((size_t)b * CH + threadIdx.x) * (size_t)NPIX;
    float s = 0.0f;
    for (int j = 0; j < TOPK; ++j) s += fb[sel[j]];
    o[threadIdx.x] = s / (float)TOPK;
}

extern "C" void kernel_launch(void* const* d_in, const int* in_sizes, int n_in,
                              void* d_out, int out_size, void* d_ws, size_t ws_size,
                              hipStream_t stream) {
    const float* feat = (const float*)d_in[0];  // (16,256,128,128) fp32
    const float* outp = (const float*)d_in[1];  // (16,2,128,128)  fp32
    const float* tau  = (const float*)d_in[2];  // scalar fp32
    float* dout = (float*)d_out;                // 2 * 16*256 fp32

    uint64_t* mask = (uint64_t*)d_ws;           // BS*WPB*2*8 = 64 KB interleaved

    mask_kernel<<<BS * (NPIX / 256), 256, 0, stream>>>(outp, tau, mask);
    sum_kernel<<<BS * CH, 256, 0, stream>>>(feat, mask, dout);
    finalize_kernel<<<2 * BS, 256, 0, stream>>>(feat, outp, mask, dout);
}